// Round 13
// baseline (35.773 us; speedup 1.0000x reference)
//
#include <hip/hip_runtime.h>

// DynamicMaskHead v13: v12 (verified math, absmax 0.046875) with the x
// preamble replaced by loads from a PRE-TRANSPOSED bf16 copy of x.
// Kernel 1 (prep_all, fused): blocks [0, N*640) transpose x[n][ch][px] f32
//   -> xt[n][px][ch] bf16 via padded LDS tile (coalesced in/out);
//   blocks [N*640, ...) pack per-instance param fragments into pk
//   (identical math to v12's prep_params).
// Kernel 2 (main): per wave = 80 px; fragment (px, ch-run-of-8) is 16
//   CONTIGUOUS bytes in xt -> preamble = 10 coalesced dwordx4 loads,
//   zero conversion VALU (was 80 scalar loads + 80 cvts).
// Instance loop: one-shot LDS param residency + stage-wise MFMA (v12).

#define CIN  64
#define HH   160
#define WW   256
#define HWSZ (HH * WW)
#define PP   1361
#define MASK_BIAS_SHIFT 2.19f
#define PKF  1280              // floats per instance in packed buffer (5120 B)
#define NSPLIT 2               // instance split across gridDim.z
#define NT   5                 // 16-px tiles per wave (80 px)
#define MAXI 8                 // max instances per split (16 / NSPLIT)
#define BLKPX (16 * NT * 4)    // 320 px per block
#define XT_OFF 524288          // byte offset of xt within d_ws (pk is 327KB)
#define PXCHUNKS (HWSZ / 64)   // 640 transpose chunks per image

typedef short short8 __attribute__((ext_vector_type(8)));
typedef float f32x4  __attribute__((ext_vector_type(4)));

union BF8 { short8 s; __bf16 b[8]; };

__device__ inline __bf16 bhi(float v) { return (__bf16)v; }
__device__ inline __bf16 blo(float v) { return (__bf16)(v - (float)(__bf16)v); }

// packed float offsets per instance:
//   0: a00 (W0 x-ch 0..31)   256: a01 (x-ch 32..63)   512: a1b (W1 + b1 ch)
//   768: a2r (replicated w2 + b2 ch)   1024: ca (coord/b0 ch)

__global__ __launch_bounds__(256) void prep_all(
    const float* __restrict__ x,
    const float* __restrict__ params,
    float*       __restrict__ pk,
    short*       __restrict__ xt,
    int N, int T, int ntrb)
{
    const int tid = threadIdx.x;

    if ((int)blockIdx.x >= ntrb) {
        // ---- param packing: 4 instances per block, one per wave
        const int t = (blockIdx.x - ntrb) * 4 + (tid >> 6);
        if (t >= T) return;
        const int lane = tid & 63;
        const int col  = lane & 15;
        const int g    = lane >> 4;
        const float* pw = params + (size_t)t * PP;
        float* dst = pk + (size_t)t * PKF;
        const __bf16 z = (__bf16)0.f;

        BF8 a00, a01;
#pragma unroll
        for (int j = 0; j < 8; ++j) {
            a00.b[j] = (__bf16)pw[col * 66 + 2 +      g * 8 + j];
            a01.b[j] = (__bf16)pw[col * 66 + 2 + 32 + g * 8 + j];
        }

        BF8 a1b;                               // W1 (k=0..15) + b1 bias channel
#pragma unroll
        for (int j = 0; j < 4; ++j)
            a1b.b[j] = (__bf16)pw[1056 + col * 16 + g * 4 + j];
        {
            const float b1 = pw[1344 + col];
            a1b.b[4] = (g == 0) ? bhi(b1) : z;
            a1b.b[5] = (g == 0) ? blo(b1) : z;
            a1b.b[6] = z;  a1b.b[7] = z;
        }

        BF8 a2r;                // w2 replicated across rows + b2 bias channel
#pragma unroll
        for (int j = 0; j < 4; ++j) a2r.b[j] = (__bf16)pw[1312 + g * 4 + j];
        {
            const float b2 = pw[1360] - MASK_BIAS_SHIFT;
            a2r.b[4] = (g == 0) ? bhi(b2) : z;
            a2r.b[5] = (g == 0) ? blo(b2) : z;
            a2r.b[6] = z;  a2r.b[7] = z;
        }

        BF8 ca;   // [wx_hi,wx_lo,wy_hi,wy_lo,b0_hi,b0_lo,0,0] on g==0 lanes
        {
            const float wx = pw[col * 66 + 0];
            const float wy = pw[col * 66 + 1];
            const float b0 = pw[1328 + col];
            ca.b[0] = (g == 0) ? bhi(wx) : z;
            ca.b[1] = (g == 0) ? blo(wx) : z;
            ca.b[2] = (g == 0) ? bhi(wy) : z;
            ca.b[3] = (g == 0) ? blo(wy) : z;
            ca.b[4] = (g == 0) ? bhi(b0) : z;
            ca.b[5] = (g == 0) ? blo(b0) : z;
            ca.b[6] = z; ca.b[7] = z;
        }

        ((short8*)(dst       ))[lane] = a00.s;
        ((short8*)(dst +  256))[lane] = a01.s;
        ((short8*)(dst +  512))[lane] = a1b.s;
        ((short8*)(dst +  768))[lane] = a2r.s;
        ((short8*)(dst + 1024))[lane] = ca.s;
        return;
    }

    // ---- x transpose: block handles 64 px x 64 ch of image n
    __shared__ float tile[CIN][65];            // +1 pad: conflict-free columns
    const int n   = blockIdx.x / PXCHUNKS;
    const int px0 = (blockIdx.x % PXCHUNKS) * 64;
    const float* src = x + (size_t)n * CIN * HWSZ + px0;

    // load: 1024 float4 slots (64 ch x 16 f4), coalesced along px
#pragma unroll
    for (int k = 0; k < 4; ++k) {
        const int idx = k * 256 + tid;
        const int ch  = idx >> 4;
        const int f4  = idx & 15;
        const f32x4 v = *(const f32x4*)(src + (size_t)ch * HWSZ + f4 * 4);
        tile[ch][f4 * 4 + 0] = v[0];
        tile[ch][f4 * 4 + 1] = v[1];
        tile[ch][f4 * 4 + 2] = v[2];
        tile[ch][f4 * 4 + 3] = v[3];
    }
    __syncthreads();

    // write: thread -> (px = tid/4, 16-ch chunk q = tid&3): 32 B coalesced
    {
        const int px = tid >> 2;
        const int q  = tid & 3;
        BF8 lo, hi;
#pragma unroll
        for (int i = 0; i < 8; ++i) {
            lo.b[i] = (__bf16)tile[q * 16 + i    ][px];
            hi.b[i] = (__bf16)tile[q * 16 + i + 8][px];
        }
        short* dst = xt + ((size_t)n * HWSZ + px0 + px) * CIN + q * 16;
        *(short8*)(dst    ) = lo.s;
        *(short8*)(dst + 8) = hi.s;
    }
}

__global__ __launch_bounds__(256, 4) void mask_head_v13(
    const short* __restrict__ xt,
    const float* __restrict__ pk,
    const int*   __restrict__ num_ins,
    float*       __restrict__ out,
    int N, int T)
{
    __shared__ __align__(16) float plds[MAXI][PKF];   // 40960 B

    const int tid  = threadIdx.x;
    const int wave = tid >> 6;
    const int lane = tid & 63;
    const int col  = lane & 15;
    const int g    = lane >> 4;
    const int n    = blockIdx.y;
    const int s    = blockIdx.z;
    const int pxw  = blockIdx.x * BLKPX + wave * (16 * NT);

    // instance range for this image (repeat-pad on last image)
    int t0 = 0;
    for (int j = 0; j < n; ++j) t0 += num_ins[j];
    int t1 = t0 + num_ins[n];
    if (n == N - 1) t1 = T;
    if (t1 > T) t1 = T;
    t0 = __builtin_amdgcn_readfirstlane(t0);
    t1 = __builtin_amdgcn_readfirstlane(t1);
    const int M = t1 - t0;

    // instances of this split: t = t0 + s + NSPLIT*i, i in [0, mloc)
    int mloc = (M - s + NSPLIT - 1) / NSPLIT;
    if (mloc < 0) mloc = 0;
    if (mloc > MAXI) mloc = MAXI;

    // ---- one-shot staging: all mloc instances' packed params -> LDS
    for (int c = tid; c < mloc * (PKF / 4); c += 256) {
        const int i   = c / (PKF / 4);
        const int off = c - i * (PKF / 4);
        const int t   = t0 + s + NSPLIT * i;
        ((f32x4*)plds[i])[off] = ((const f32x4*)(pk + (size_t)t * PKF))[off];
    }

    // x fragments from transposed bf16: 10 coalesced 16B loads, no cvt
    BF8 xb[NT][2];
    const short* xtp = xt + ((size_t)n * HWSZ + pxw) * CIN;
#pragma unroll
    for (int nt = 0; nt < NT; ++nt)
#pragma unroll
        for (int c = 0; c < 2; ++c)
            xb[nt][c].s = *(const short8*)(xtp + (nt * 16 + col) * CIN + c * 32 + g * 8);

    // coordinate B-fragments (instance-independent): [xf,xf,yf,yf,1,1,0,0]
    BF8 b2c[NT];
#pragma unroll
    for (int nt = 0; nt < NT; ++nt) {
        const int px = pxw + nt * 16 + col;
        const __bf16 xfb = (__bf16)(float)(px & (WW - 1));
        const __bf16 yfb = (__bf16)(float)(px >> 8);
        b2c[nt].b[0] = xfb; b2c[nt].b[1] = xfb;
        b2c[nt].b[2] = yfb; b2c[nt].b[3] = yfb;
        b2c[nt].b[4] = (__bf16)1.f; b2c[nt].b[5] = (__bf16)1.f;
        b2c[nt].b[6] = (__bf16)0.f; b2c[nt].b[7] = (__bf16)0.f;
    }

    const __bf16 one = (__bf16)1.f, zero = (__bf16)0.f;
    __syncthreads();   // params staged

    // ---- instance loop: stage-wise across all 5 tiles (5-way chain ILP)
    for (int i = 0; i < mloc; ++i) {
        const int t = t0 + s + NSPLIT * i;
        const short8* fp = (const short8*)plds[i];

        short8 ca  = fp[256 + lane];
        short8 a00 = fp[       lane];
        short8 a01 = fp[ 64 + lane];

        f32x4 acc[NT];
#pragma unroll
        for (int nt = 0; nt < NT; ++nt) {
            f32x4 z4 = {0.f, 0.f, 0.f, 0.f};
            acc[nt] = __builtin_amdgcn_mfma_f32_16x16x32_bf16(ca, b2c[nt].s, z4, 0, 0, 0);
        }
#pragma unroll
        for (int nt = 0; nt < NT; ++nt)
            acc[nt] = __builtin_amdgcn_mfma_f32_16x16x32_bf16(a00, xb[nt][0].s, acc[nt], 0, 0, 0);
#pragma unroll
        for (int nt = 0; nt < NT; ++nt)
            acc[nt] = __builtin_amdgcn_mfma_f32_16x16x32_bf16(a01, xb[nt][1].s, acc[nt], 0, 0, 0);

        BF8 h[NT];
#pragma unroll
        for (int nt = 0; nt < NT; ++nt) {
#pragma unroll
            for (int j = 0; j < 4; ++j) h[nt].b[j] = (__bf16)fmaxf(acc[nt][j], 0.f);
            h[nt].b[4] = one; h[nt].b[5] = one; h[nt].b[6] = zero; h[nt].b[7] = zero;
        }

        short8 a1b = fp[128 + lane];
#pragma unroll
        for (int nt = 0; nt < NT; ++nt) {
            f32x4 z4 = {0.f, 0.f, 0.f, 0.f};
            acc[nt] = __builtin_amdgcn_mfma_f32_16x16x32_bf16(a1b, h[nt].s, z4, 0, 0, 0);
        }

#pragma unroll
        for (int nt = 0; nt < NT; ++nt) {
#pragma unroll
            for (int j = 0; j < 4; ++j) h[nt].b[j] = (__bf16)fmaxf(acc[nt][j], 0.f);
            h[nt].b[4] = one; h[nt].b[5] = one; h[nt].b[6] = zero; h[nt].b[7] = zero;
        }

        short8 a2r = fp[192 + lane];
#pragma unroll
        for (int nt = 0; nt < NT; ++nt) {
            f32x4 z4 = {0.f, 0.f, 0.f, 0.f};
            acc[nt] = __builtin_amdgcn_mfma_f32_16x16x32_bf16(a2r, h[nt].s, z4, 0, 0, 0);
        }

        float oval = 0.f, t4 = 0.f;
#pragma unroll
        for (int nt = 0; nt < NT; ++nt) {
            if (nt == g)  oval = acc[nt][0];
            if (nt == 4)  t4   = acc[nt][0];
        }
        float* const op = out + (size_t)t * HWSZ + pxw;
        op[lane] = oval;                      // 64-lane coalesced (tiles 0-3)
        if (g == 0) op[64 + col] = t4;        // 16-lane store (tile 4)
    }
}

// ---- fallback (no workspace): round-2-style kernel, params from global
__global__ __launch_bounds__(256) void mask_head_mfma_nows(
    const float* __restrict__ x,
    const float* __restrict__ params,
    const int*   __restrict__ num_ins,
    float*       __restrict__ out,
    int N, int T)
{
    const int tid  = threadIdx.x;
    const int wave = tid >> 6;
    const int lane = tid & 63;
    const int col  = lane & 15;
    const int g    = lane >> 4;
    const int n    = blockIdx.y;
    const int pxw  = blockIdx.x * 256 + wave * 64;

    int t0 = 0;
    for (int j = 0; j < n; ++j) t0 += num_ins[j];
    int t1 = t0 + num_ins[n];
    if (n == N - 1) t1 = T;
    if (t1 > T) t1 = T;

    BF8 xb[4][2];
    const float* xbase = x + (size_t)n * CIN * HWSZ + pxw + col;
#pragma unroll
    for (int nt = 0; nt < 4; ++nt)
#pragma unroll
        for (int c = 0; c < 2; ++c)
#pragma unroll
            for (int j = 0; j < 8; ++j)
                xb[nt][c].b[j] = (__bf16)xbase[(size_t)(c * 32 + g * 8 + j) * HWSZ + nt * 16];

    float xf[4], yf[4];
#pragma unroll
    for (int nt = 0; nt < 4; ++nt) {
        const int pix = pxw + nt * 16 + col;
        xf[nt] = (float)(pix & (WW - 1));
        yf[nt] = (float)(pix >> 8);
    }

    for (int t = t0; t < t1; ++t) {
        const float* pw = params + (size_t)t * PP;
        BF8 a00, a01, a1;
#pragma unroll
        for (int j = 0; j < 8; ++j) {
            a00.b[j] = (__bf16)pw[col * 66 + 2 +      g * 8 + j];
            a01.b[j] = (__bf16)pw[col * 66 + 2 + 32 + g * 8 + j];
        }
#pragma unroll
        for (int j = 0; j < 4; ++j) {
            a1.b[j]     = (__bf16)pw[1056 + col * 16 + g * 4 + j];
            a1.b[4 + j] = (__bf16)0.f;
        }
        float wxv[4], wyv[4], b0v[4], b1v[4], w2v[4];
#pragma unroll
        for (int j = 0; j < 4; ++j) {
            const int r = g * 4 + j;
            wxv[j] = pw[r * 66 + 0];
            wyv[j] = pw[r * 66 + 1];
            b0v[j] = pw[1328 + r];
            b1v[j] = pw[1344 + r];
            w2v[j] = pw[1312 + r];
        }
        const float b2v = pw[1360] - MASK_BIAS_SHIFT;

        f32x4 acc0[4];
#pragma unroll
        for (int nt = 0; nt < 4; ++nt) {
            f32x4 a = {0.f, 0.f, 0.f, 0.f};
            a = __builtin_amdgcn_mfma_f32_16x16x32_bf16(a00.s, xb[nt][0].s, a, 0, 0, 0);
            a = __builtin_amdgcn_mfma_f32_16x16x32_bf16(a01.s, xb[nt][1].s, a, 0, 0, 0);
            acc0[nt] = a;
        }
        BF8 h0[4];
#pragma unroll
        for (int nt = 0; nt < 4; ++nt)
#pragma unroll
            for (int j = 0; j < 4; ++j) {
                float v = acc0[nt][j] + b0v[j];
                v = fmaf(wxv[j], xf[nt], v);
                v = fmaf(wyv[j], yf[nt], v);
                v = fmaxf(v, 0.f);
                h0[nt].b[j]     = (__bf16)v;
                h0[nt].b[4 + j] = (__bf16)0.f;
            }
        f32x4 acc1[4];
#pragma unroll
        for (int nt = 0; nt < 4; ++nt) {
            f32x4 a = {0.f, 0.f, 0.f, 0.f};
            acc1[nt] = __builtin_amdgcn_mfma_f32_16x16x32_bf16(a1.s, h0[nt].s, a, 0, 0, 0);
        }
        float oval = 0.f;
#pragma unroll
        for (int nt = 0; nt < 4; ++nt) {
            float sum = 0.f;
#pragma unroll
            for (int j = 0; j < 4; ++j) {
                const float h = fmaxf(acc1[nt][j] + b1v[j], 0.f);
                sum = fmaf(w2v[j], h, sum);
            }
            sum += __shfl_xor(sum, 16, 64);
            sum += __shfl_xor(sum, 32, 64);
            if (nt == g) oval = sum + b2v;
        }
        out[(size_t)t * HWSZ + pxw + lane] = oval;
    }
}

extern "C" void kernel_launch(void* const* d_in, const int* in_sizes, int n_in,
                              void* d_out, int out_size, void* d_ws, size_t ws_size,
                              hipStream_t stream) {
    const float* x      = (const float*)d_in[0];
    const float* params = (const float*)d_in[1];
    const int*   nins   = (const int*)d_in[2];
    float*       out    = (float*)d_out;

    const int N = in_sizes[2];            // images
    const int T = in_sizes[1] / PP;       // total instances (param rows)
    const int ntrb = N * PXCHUNKS;        // transpose blocks
    const size_t ws_needed = (size_t)XT_OFF + (size_t)N * HWSZ * CIN * 2;

    if (ws_size >= ws_needed) {
        float* pk = (float*)d_ws;
        short* xt = (short*)((char*)d_ws + XT_OFF);
        prep_all<<<ntrb + (T + 3) / 4, dim3(256), 0, stream>>>(
            x, params, pk, xt, N, T, ntrb);
        dim3 grid(HWSZ / BLKPX, N, NSPLIT);   // 128 x 4 x 2 = 1024 blocks
        mask_head_v13<<<grid, dim3(256), 0, stream>>>(xt, pk, nins, out, N, T);
    } else {
        dim3 grid(HWSZ / 256, N);
        mask_head_mfma_nows<<<grid, dim3(256), 0, stream>>>(x, params, nins, out, N, T);
    }
}

// Round 14
// 27.270 us; speedup vs baseline: 1.3118x; 1.3118x over previous
//
#include <hip/hip_runtime.h>

// DynamicMaskHead v14: SINGLE-LAUNCH fusion. Each block packs its 8
// instances' param fragments directly from raw params into LDS (same math
// as the old prep_params, absmax 0.046875 verified since round 5), then
// runs the v12 stage-wise all-MFMA instance loop. No workspace, no second
// kernel, no prep->main dependency.
// Block = 4 waves x 80 px = 320 px; grid = 128 x 4 images x NSPLIT(2)
// = 1024 blocks = 4 blocks/CU; LDS 40960 B = 160 KiB/CU at 4 blocks.
// Per (instance, 16-px tile): 5 MFMAs, zero shuffles:
//   acc = ca*coords + W0a*X + W0b*X ; relu/cvt ; a1b MFMA (b1 channel);
//   relu/cvt ; a2r MFMA (row-replicated w2 + b2 channel) -> acc[0] = out.

#define CIN  64
#define HH   160
#define WW   256
#define HWSZ (HH * WW)
#define PP   1361
#define MASK_BIAS_SHIFT 2.19f
#define PKF  1280              // floats per instance in LDS block (5120 B)
#define NSPLIT 2               // instance split across gridDim.z
#define NT   5                 // 16-px tiles per wave (80 px)
#define MAXI 8                 // max instances per split (16 / NSPLIT)
#define BLKPX (16 * NT * 4)    // 320 px per block

typedef short short8 __attribute__((ext_vector_type(8)));
typedef float f32x4  __attribute__((ext_vector_type(4)));

union BF8 { short8 s; __bf16 b[8]; };

__device__ inline __bf16 bhi(float v) { return (__bf16)v; }
__device__ inline __bf16 blo(float v) { return (__bf16)(v - (float)(__bf16)v); }

// LDS float offsets per instance slot:
//   0: a00 (W0 x-ch 0..31)   256: a01 (x-ch 32..63)   512: a1b (W1 + b1 ch)
//   768: a2r (replicated w2 + b2 ch)   1024: ca (coord/b0 ch)

__device__ __forceinline__ void pack_one(const float* __restrict__ pw,
                                         int lane, float* __restrict__ dst)
{
    const int col = lane & 15;
    const int g   = lane >> 4;
    const __bf16 z = (__bf16)0.f;

    BF8 a00, a01;
#pragma unroll
    for (int j = 0; j < 8; ++j) {
        a00.b[j] = (__bf16)pw[col * 66 + 2 +      g * 8 + j];
        a01.b[j] = (__bf16)pw[col * 66 + 2 + 32 + g * 8 + j];
    }

    BF8 a1b;                                   // W1 (k=0..15) + b1 bias channel
#pragma unroll
    for (int j = 0; j < 4; ++j)
        a1b.b[j] = (__bf16)pw[1056 + col * 16 + g * 4 + j];
    {
        const float b1 = pw[1344 + col];
        a1b.b[4] = (g == 0) ? bhi(b1) : z;
        a1b.b[5] = (g == 0) ? blo(b1) : z;
        a1b.b[6] = z;  a1b.b[7] = z;
    }

    BF8 a2r;                    // w2 replicated across rows + b2 bias channel
#pragma unroll
    for (int j = 0; j < 4; ++j) a2r.b[j] = (__bf16)pw[1312 + g * 4 + j];
    {
        const float b2 = pw[1360] - MASK_BIAS_SHIFT;
        a2r.b[4] = (g == 0) ? bhi(b2) : z;
        a2r.b[5] = (g == 0) ? blo(b2) : z;
        a2r.b[6] = z;  a2r.b[7] = z;
    }

    BF8 ca;   // [wx_hi,wx_lo,wy_hi,wy_lo,b0_hi,b0_lo,0,0] on g==0 lanes
    {
        const float wx = pw[col * 66 + 0];
        const float wy = pw[col * 66 + 1];
        const float b0 = pw[1328 + col];
        ca.b[0] = (g == 0) ? bhi(wx) : z;
        ca.b[1] = (g == 0) ? blo(wx) : z;
        ca.b[2] = (g == 0) ? bhi(wy) : z;
        ca.b[3] = (g == 0) ? blo(wy) : z;
        ca.b[4] = (g == 0) ? bhi(b0) : z;
        ca.b[5] = (g == 0) ? blo(b0) : z;
        ca.b[6] = z; ca.b[7] = z;
    }

    ((short8*)(dst       ))[lane] = a00.s;
    ((short8*)(dst +  256))[lane] = a01.s;
    ((short8*)(dst +  512))[lane] = a1b.s;
    ((short8*)(dst +  768))[lane] = a2r.s;
    ((short8*)(dst + 1024))[lane] = ca.s;
}

__global__ __launch_bounds__(256, 4) void mask_head_v14(
    const float* __restrict__ x,
    const float* __restrict__ params,
    const int*   __restrict__ num_ins,
    float*       __restrict__ out,
    int N, int T)
{
    __shared__ __align__(16) float plds[MAXI][PKF];   // 40960 B

    const int tid  = threadIdx.x;
    const int wave = tid >> 6;
    const int lane = tid & 63;
    const int col  = lane & 15;
    const int g    = lane >> 4;
    const int n    = blockIdx.y;
    const int s    = blockIdx.z;
    const int pxw  = blockIdx.x * BLKPX + wave * (16 * NT);

    // instance range for this image (repeat-pad on last image)
    int t0 = 0;
    for (int j = 0; j < n; ++j) t0 += num_ins[j];
    int t1 = t0 + num_ins[n];
    if (n == N - 1) t1 = T;
    if (t1 > T) t1 = T;
    t0 = __builtin_amdgcn_readfirstlane(t0);
    t1 = __builtin_amdgcn_readfirstlane(t1);
    const int M = t1 - t0;

    // instances of this split: t = t0 + s + NSPLIT*i, i in [0, mloc)
    int mloc = (M - s + NSPLIT - 1) / NSPLIT;
    if (mloc < 0) mloc = 0;
    if (mloc > MAXI) mloc = MAXI;

    // ---- in-block packing: wave w packs instance slots {w, w+4}
#pragma unroll
    for (int k = 0; k < 2; ++k) {
        const int i = wave + k * 4;
        if (i < mloc) {
            const int t = t0 + s + NSPLIT * i;
            pack_one(params + (size_t)t * PP, lane, plds[i]);
        }
    }

    // x fragments: 80 px x 64 ch (40 VGPR); global-load latency overlaps
    // the other waves' packing (no LDS dependency until the barrier)
    BF8 xb[NT][2];
    const float* xbase = x + (size_t)n * CIN * HWSZ + pxw + col;
#pragma unroll
    for (int nt = 0; nt < NT; ++nt)
#pragma unroll
        for (int c = 0; c < 2; ++c)
#pragma unroll
            for (int j = 0; j < 8; ++j) {
                const int ch = c * 32 + g * 8 + j;
                xb[nt][c].b[j] = (__bf16)xbase[(size_t)ch * HWSZ + nt * 16];
            }

    // coordinate B-fragments (instance-independent): [xf,xf,yf,yf,1,1,0,0]
    BF8 b2c[NT];
#pragma unroll
    for (int nt = 0; nt < NT; ++nt) {
        const int px = pxw + nt * 16 + col;
        const __bf16 xfb = (__bf16)(float)(px & (WW - 1));
        const __bf16 yfb = (__bf16)(float)(px >> 8);
        b2c[nt].b[0] = xfb; b2c[nt].b[1] = xfb;
        b2c[nt].b[2] = yfb; b2c[nt].b[3] = yfb;
        b2c[nt].b[4] = (__bf16)1.f; b2c[nt].b[5] = (__bf16)1.f;
        b2c[nt].b[6] = (__bf16)0.f; b2c[nt].b[7] = (__bf16)0.f;
    }

    const __bf16 one = (__bf16)1.f, zero = (__bf16)0.f;
    __syncthreads();   // all packing visible

    // ---- instance loop: stage-wise across all 5 tiles (5-way chain ILP)
    for (int i = 0; i < mloc; ++i) {
        const int t = t0 + s + NSPLIT * i;
        const short8* fp = (const short8*)plds[i];

        short8 ca  = fp[256 + lane];
        short8 a00 = fp[       lane];
        short8 a01 = fp[ 64 + lane];

        f32x4 acc[NT];
#pragma unroll
        for (int nt = 0; nt < NT; ++nt) {
            f32x4 z4 = {0.f, 0.f, 0.f, 0.f};
            acc[nt] = __builtin_amdgcn_mfma_f32_16x16x32_bf16(ca, b2c[nt].s, z4, 0, 0, 0);
        }
#pragma unroll
        for (int nt = 0; nt < NT; ++nt)
            acc[nt] = __builtin_amdgcn_mfma_f32_16x16x32_bf16(a00, xb[nt][0].s, acc[nt], 0, 0, 0);
#pragma unroll
        for (int nt = 0; nt < NT; ++nt)
            acc[nt] = __builtin_amdgcn_mfma_f32_16x16x32_bf16(a01, xb[nt][1].s, acc[nt], 0, 0, 0);

        BF8 h[NT];
#pragma unroll
        for (int nt = 0; nt < NT; ++nt) {
#pragma unroll
            for (int j = 0; j < 4; ++j) h[nt].b[j] = (__bf16)fmaxf(acc[nt][j], 0.f);
            h[nt].b[4] = one; h[nt].b[5] = one; h[nt].b[6] = zero; h[nt].b[7] = zero;
        }

        short8 a1b = fp[128 + lane];
#pragma unroll
        for (int nt = 0; nt < NT; ++nt) {
            f32x4 z4 = {0.f, 0.f, 0.f, 0.f};
            acc[nt] = __builtin_amdgcn_mfma_f32_16x16x32_bf16(a1b, h[nt].s, z4, 0, 0, 0);
        }

#pragma unroll
        for (int nt = 0; nt < NT; ++nt) {
#pragma unroll
            for (int j = 0; j < 4; ++j) h[nt].b[j] = (__bf16)fmaxf(acc[nt][j], 0.f);
            h[nt].b[4] = one; h[nt].b[5] = one; h[nt].b[6] = zero; h[nt].b[7] = zero;
        }

        short8 a2r = fp[192 + lane];
#pragma unroll
        for (int nt = 0; nt < NT; ++nt) {
            f32x4 z4 = {0.f, 0.f, 0.f, 0.f};
            acc[nt] = __builtin_amdgcn_mfma_f32_16x16x32_bf16(a2r, h[nt].s, z4, 0, 0, 0);
        }

        float oval = 0.f, t4 = 0.f;
#pragma unroll
        for (int nt = 0; nt < NT; ++nt) {
            if (nt == g)  oval = acc[nt][0];
            if (nt == 4)  t4   = acc[nt][0];
        }
        float* const op = out + (size_t)t * HWSZ + pxw;
        op[lane] = oval;                      // 64-lane coalesced (tiles 0-3)
        if (g == 0) op[64 + col] = t4;        // 16-lane store (tile 4)
    }
}

extern "C" void kernel_launch(void* const* d_in, const int* in_sizes, int n_in,
                              void* d_out, int out_size, void* d_ws, size_t ws_size,
                              hipStream_t stream) {
    const float* x      = (const float*)d_in[0];
    const float* params = (const float*)d_in[1];
    const int*   nins   = (const int*)d_in[2];
    float*       out    = (float*)d_out;

    const int N = in_sizes[2];            // images
    const int T = in_sizes[1] / PP;       // total instances (param rows)

    dim3 grid(HWSZ / BLKPX, N, NSPLIT);   // 128 x 4 x 2 = 1024 blocks
    mask_head_v14<<<grid, dim3(256), 0, stream>>>(x, params, nins, out, N, T);
}